// Round 3
// baseline (283.426 us; speedup 1.0000x reference)
//
#include <hip/hip_runtime.h>
#include <math.h>

#define NFEAT 4096
#define M     2048
#define THREADS 256
#define ROWS_PER_WG 4

// XOR swizzle: bijective on [0,2048); keeps lane-contiguous reads conflict-free
// and spreads the stride-8 stage-1 writes uniformly across bank pairs.
#define SWZ(i) ((i) ^ (((i) >> 4) & 15))

__device__ __forceinline__ float2 cmul(float2 a, float2 b){
    return make_float2(a.x*b.x - a.y*b.y, a.x*b.y + a.y*b.x);
}
__device__ __forceinline__ float2 cadd(float2 a, float2 b){ return make_float2(a.x+b.x, a.y+b.y); }
__device__ __forceinline__ float2 csub(float2 a, float2 b){ return make_float2(a.x-b.x, a.y-b.y); }

// 4-point DFT, sign = -1 forward (e^{-2pi i rk/4}), +1 inverse.
template<int SIGN>
__device__ __forceinline__ void fft4(float2& a0, float2& a1, float2& a2, float2& a3){
    float2 t0 = cadd(a0,a2), t1 = csub(a0,a2);
    float2 t2 = cadd(a1,a3), t3 = csub(a1,a3);
    // SIGN<0: -i*t3 = (t3.y, -t3.x); SIGN>0: +i*t3 = (-t3.y, t3.x)
    float2 r3 = (SIGN < 0) ? make_float2(t3.y, -t3.x) : make_float2(-t3.y, t3.x);
    a0 = cadd(t0,t2); a2 = csub(t0,t2);
    a1 = cadd(t1,r3); a3 = csub(t1,r3);
}

template<int SIGN>
__device__ __forceinline__ void fft8(float2 v[8]){
    const float C = 0.70710678118654752440f;
    float2 e0=v[0], e1=v[2], e2=v[4], e3=v[6];
    float2 o0=v[1], o1=v[3], o2=v[5], o3=v[7];
    fft4<SIGN>(e0,e1,e2,e3);
    fft4<SIGN>(o0,o1,o2,o3);
    float2 w1 = make_float2( C, (SIGN<0) ? -C : C);   // w8^1
    float2 w3 = make_float2(-C, (SIGN<0) ? -C : C);   // w8^3
    float2 o1w = cmul(o1, w1);
    float2 o2w = (SIGN<0) ? make_float2(o2.y, -o2.x) : make_float2(-o2.y, o2.x); // w8^2 = -/+ i
    float2 o3w = cmul(o3, w3);
    v[0]=cadd(e0,o0);  v[4]=csub(e0,o0);
    v[1]=cadd(e1,o1w); v[5]=csub(e1,o1w);
    v[2]=cadd(e2,o2w); v[6]=csub(e2,o2w);
    v[3]=cadd(e3,o3w); v[7]=csub(e3,o3w);
}

// One Stockham radix-8 stage over N=2048: butterfly j in [0,256).
// tw holds e^{-2pi i t/2048} for t in [0,1024); t>=1024 -> negate.
template<int SIGN, int NS>
__device__ __forceinline__ void stage8(const float2* __restrict__ src, float2* __restrict__ dst,
                                       const float2* __restrict__ tw, int j){
    const int m  = j & (NS - 1);
    const int tb = m * (M / (NS * 8));
    float2 v[8];
#pragma unroll
    for (int r = 0; r < 8; ++r){
        float2 a = src[SWZ(j + 256*r)];
        if (NS == 1 || r == 0){
            v[r] = a;
        } else {
            int tt = tb * r;                 // < 2048 by construction
            float2 w = tw[tt & 1023];
            float s = (tt & 1024) ? -1.f : 1.f;
            w.x *= s;
            w.y = (SIGN < 0) ? w.y * s : -w.y * s;   // conj for inverse
            v[r] = cmul(a, w);
        }
    }
    fft8<SIGN>(v);
    const int idxD = ((j - m) << 3) + m;     // (j/NS)*NS*8 + m
#pragma unroll
    for (int r = 0; r < 8; ++r)
        dst[SWZ(idxD + NS*r)] = v[r];
}

// Stockham radix-4 stage: butterfly j in [0,512).
template<int SIGN, int NS>
__device__ __forceinline__ void stage4(const float2* __restrict__ src, float2* __restrict__ dst,
                                       const float2* __restrict__ tw, int j){
    const int m  = j & (NS - 1);
    const int tb = m * (M / (NS * 4));
    float2 v[4];
#pragma unroll
    for (int r = 0; r < 4; ++r){
        float2 a = src[SWZ(j + 512*r)];
        if (r == 0){ v[r] = a; }
        else {
            int tt = tb * r;
            float2 w = tw[tt & 1023];
            float s = (tt & 1024) ? -1.f : 1.f;
            w.x *= s;
            w.y = (SIGN < 0) ? w.y * s : -w.y * s;
            v[r] = cmul(a, w);
        }
    }
    fft4<SIGN>(v[0], v[1], v[2], v[3]);
    const int idxD = ((j - m) << 2) + m;
#pragma unroll
    for (int r = 0; r < 4; ++r)
        dst[SWZ(idxD + NS*r)] = v[r];
}

extern "C" __global__ void __launch_bounds__(THREADS)
rfft_circ_kernel(const float* __restrict__ x,
                 const float* __restrict__ Hr,
                 const float* __restrict__ Hi,
                 const float* __restrict__ bias,
                 float* __restrict__ out)
{
    __shared__ float2 bufA[M];
    __shared__ float2 bufB[M];
    __shared__ float2 tw1[1024];  // e^{-2pi i t/2048}, t<1024
    __shared__ float2 tw2[1024];  // e^{-2pi i k/4096}, k<1024

    const int t = threadIdx.x;

    for (int i = t; i < 1024; i += THREADS){
        float s, c;
        sincosf(-6.2831853071795864769f * (float)i * (1.0f/2048.0f), &s, &c);
        tw1[i] = make_float2(c, s);
        sincosf(-6.2831853071795864769f * (float)i * (1.0f/4096.0f), &s, &c);
        tw2[i] = make_float2(c, s);
    }
    __syncthreads();

#pragma unroll 1
    for (int rr = 0; rr < ROWS_PER_WG; ++rr){
        const int row = blockIdx.x * ROWS_PER_WG + rr;
        const float4* xr = (const float4*)(x + (size_t)row * NFEAT);

        // Load row, pack pairs into complex: bufA[m] = x[2m] + i x[2m+1]
#pragma unroll
        for (int q = 0; q < 4; ++q){
            int u = t + THREADS*q;
            float4 d = xr[u];
            bufA[SWZ(2*u)]   = make_float2(d.x, d.y);
            bufA[SWZ(2*u+1)] = make_float2(d.z, d.w);
        }
        __syncthreads();

        // Forward complex FFT-2048 (unnormalized, sign -1), Stockham: Ns = 1,8,64,512
        stage8<-1,1  >(bufA, bufB, tw1, t); __syncthreads();
        stage8<-1,8  >(bufB, bufA, tw1, t); __syncthreads();
        stage8<-1,64 >(bufA, bufB, tw1, t); __syncthreads();
        stage4<-1,512>(bufB, bufA, tw1, t);
        stage4<-1,512>(bufB, bufA, tw1, t + 256);
        __syncthreads();

        // Spectral: untangle rfft bins (k<1024; rest masked), apply H, retangle
        // into the packed inverse-spectrum Zy.  Z in bufA -> Zy in bufB.
#pragma unroll
        for (int q = 0; q < 4; ++q){
            int k = t + THREADS*q;
            if (k == 0){
                float2 z0 = bufA[SWZ(0)];
                float X0 = z0.x + z0.y;          // real DC of the length-4096 rfft
                float Y0 = X0 * Hr[0];           // H[0] imag forced to 0
                bufB[SWZ(0)]    = make_float2(0.5f*Y0, 0.5f*Y0);   // 0.5*Y0*(1+i)
                bufB[SWZ(1024)] = make_float2(0.f, 0.f);           // bin M/2: masked
            } else {
                float2 zk = bufA[SWZ(k)];
                float2 zm = bufA[SWZ(2048 - k)];
                float2 w  = tw2[k];                          // e^{-2pi i k/4096}
                // A = (Z[k]+conj(Z[M-k]))/2 ; B = (Z[k]-conj(Z[M-k]))/2
                float2 A = make_float2(0.5f*(zk.x + zm.x), 0.5f*(zk.y - zm.y));
                float2 B = make_float2(0.5f*(zk.x - zm.x), 0.5f*(zk.y + zm.y));
                // X[k] = A - i*w*B
                float2 wB = cmul(w, B);
                float2 X = make_float2(A.x + wB.y, A.y - wB.x);
                float2 H = make_float2(Hr[k], Hi[k]);
                float2 Y = cmul(X, H);
                // Zy[k]      = 0.5*Y*(1 + i*conj(w))   (Y[M-k] masked to 0)
                // Zy[2048-k] = 0.5*conj(Y)*(1 + i*w)
                float2 f1 = make_float2(1.f + w.y,  w.x);
                float2 f2 = make_float2(1.f - w.y,  w.x);
                float2 Yc = make_float2(Y.x, -Y.y);
                float2 zy1 = cmul(Y,  f1);
                float2 zy2 = cmul(Yc, f2);
                bufB[SWZ(k)]        = make_float2(0.5f*zy1.x, 0.5f*zy1.y);
                bufB[SWZ(2048 - k)] = make_float2(0.5f*zy2.x, 0.5f*zy2.y);
            }
        }
        __syncthreads();

        // Inverse complex FFT-2048 (unnormalized, sign +1)
        stage8<1,1  >(bufB, bufA, tw1, t); __syncthreads();
        stage8<1,8  >(bufA, bufB, tw1, t); __syncthreads();
        stage8<1,64 >(bufB, bufA, tw1, t); __syncthreads();
        stage4<1,512>(bufA, bufB, tw1, t);
        stage4<1,512>(bufA, bufB, tw1, t + 256);
        __syncthreads();

        // Epilogue: y[2m] = Re(z[m])/2048 + bias, y[2m+1] = Im(z[m])/2048 + bias
        float4* yr = (float4*)(out + (size_t)row * NFEAT);
        const float4* br = (const float4*)bias;
        const float inv = (1.0f/2048.0f);
#pragma unroll
        for (int q = 0; q < 4; ++q){
            int u = t + THREADS*q;
            float2 z0 = bufB[SWZ(2*u)];
            float2 z1 = bufB[SWZ(2*u+1)];
            float4 b = br[u];
            float4 o;
            o.x = fmaf(z0.x, inv, b.x);
            o.y = fmaf(z0.y, inv, b.y);
            o.z = fmaf(z1.x, inv, b.z);
            o.w = fmaf(z1.y, inv, b.w);
            yr[u] = o;
        }
        __syncthreads();  // bufB must be fully consumed before next row's stage writes it
    }
}

extern "C" void kernel_launch(void* const* d_in, const int* in_sizes, int n_in,
                              void* d_out, int out_size, void* d_ws, size_t ws_size,
                              hipStream_t stream) {
    const float* x    = (const float*)d_in[0];
    const float* Hr   = (const float*)d_in[1];
    const float* Hi   = (const float*)d_in[2];
    const float* bias = (const float*)d_in[3];
    float* out        = (float*)d_out;

    const int n_rows = in_sizes[0] / NFEAT;   // 8192 at reference shape
    dim3 grid(n_rows / ROWS_PER_WG), block(THREADS);
    hipLaunchKernelGGL(rfft_circ_kernel, grid, block, 0, stream,
                       x, Hr, Hi, bias, out);
}

// Round 4
// 271.929 us; speedup vs baseline: 1.0423x; 1.0423x over previous
//
#include <hip/hip_runtime.h>
#include <math.h>

#define NFEAT 4096
#define M     2048
#define THREADS 256
#define ROWS_PER_WG 4

// Data-buffer swizzle: bijective on [0,2048); keeps lane-contiguous reads
// conflict-free and spreads strided Stockham writes across bank pairs.
#define SWZ(i) ((i) ^ (((i) >> 4) & 15))
// Twiddle-table physical swizzle: spreads multiples-of-64 gather indices
// (stage twiddles) across bank pairs instead of all landing on pair 0.
#define TWPHYS(e) ((e) ^ (((e) >> 4) & 15))

__device__ __forceinline__ float2 cmul(float2 a, float2 b){
    return make_float2(a.x*b.x - a.y*b.y, a.x*b.y + a.y*b.x);
}
__device__ __forceinline__ float2 cadd(float2 a, float2 b){ return make_float2(a.x+b.x, a.y+b.y); }
__device__ __forceinline__ float2 csub(float2 a, float2 b){ return make_float2(a.x-b.x, a.y-b.y); }

// w2048^tt (= e^{-2pi i tt/2048}), tt in [0,2048), from quarter-4096 table.
// twq[k] = e^{-2pi i k/4096}, k<1024 (phys-swizzled).  SIGN>0 -> conjugate.
template<int SIGN>
__device__ __forceinline__ float2 tw2048(const float2* __restrict__ twq, int tt){
    int e = (tt & 511) << 1;                 // even index < 1024
    float2 w = twq[TWPHYS(e)];
    if (tt & 512)  w = make_float2(w.y, -w.x);    // * -i
    if (tt & 1024) w = make_float2(-w.x, -w.y);   // * -1
    if (SIGN > 0)  w.y = -w.y;                    // conj for inverse
    return w;
}

// 4-point DFT, sign = -1 forward, +1 inverse.
template<int SIGN>
__device__ __forceinline__ void fft4(float2& a0, float2& a1, float2& a2, float2& a3){
    float2 t0 = cadd(a0,a2), t1 = csub(a0,a2);
    float2 t2 = cadd(a1,a3), t3 = csub(a1,a3);
    float2 r3 = (SIGN < 0) ? make_float2(t3.y, -t3.x) : make_float2(-t3.y, t3.x);
    a0 = cadd(t0,t2); a2 = csub(t0,t2);
    a1 = cadd(t1,r3); a3 = csub(t1,r3);
}

template<int SIGN>
__device__ __forceinline__ void fft8(float2 v[8]){
    const float C = 0.70710678118654752440f;
    float2 e0=v[0], e1=v[2], e2=v[4], e3=v[6];
    float2 o0=v[1], o1=v[3], o2=v[5], o3=v[7];
    fft4<SIGN>(e0,e1,e2,e3);
    fft4<SIGN>(o0,o1,o2,o3);
    float2 w1 = make_float2( C, (SIGN<0) ? -C : C);
    float2 w3 = make_float2(-C, (SIGN<0) ? -C : C);
    float2 o1w = cmul(o1, w1);
    float2 o2w = (SIGN<0) ? make_float2(o2.y, -o2.x) : make_float2(-o2.y, o2.x);
    float2 o3w = cmul(o3, w3);
    v[0]=cadd(e0,o0);  v[4]=csub(e0,o0);
    v[1]=cadd(e1,o1w); v[5]=csub(e1,o1w);
    v[2]=cadd(e2,o2w); v[6]=csub(e2,o2w);
    v[3]=cadd(e3,o3w); v[7]=csub(e3,o3w);
}

// Stockham radix-8 LDS->LDS stage over N=2048: butterfly j in [0,256).
template<int SIGN, int NS>
__device__ __forceinline__ void stage8(const float2* __restrict__ src, float2* __restrict__ dst,
                                       const float2* __restrict__ twq, int j){
    const int m  = j & (NS - 1);
    const int tb = m * (M / (NS * 8));
    float2 v[8];
#pragma unroll
    for (int r = 0; r < 8; ++r){
        float2 a = src[SWZ(j + 256*r)];
        if (NS == 1 || r == 0) v[r] = a;
        else                   v[r] = cmul(a, tw2048<SIGN>(twq, tb * r));
    }
    fft8<SIGN>(v);
    const int idxD = ((j - m) << 3) + m;
#pragma unroll
    for (int r = 0; r < 8; ++r)
        dst[SWZ(idxD + NS*r)] = v[r];
}

extern "C" __global__ void __launch_bounds__(THREADS)
rfft_circ_kernel(const float* __restrict__ x,
                 const float* __restrict__ Hr,
                 const float* __restrict__ Hi,
                 const float* __restrict__ bias,
                 float* __restrict__ out)
{
    __shared__ float2 bufA[M];
    __shared__ float2 bufB[M];
    __shared__ float2 twq[1024];   // e^{-2pi i k/4096}, k<1024, phys-swizzled

    const int t = threadIdx.x;

    for (int i = t; i < 1024; i += THREADS){
        float s, c;
        sincosf(-6.2831853071795864769f * (float)i * (1.0f/4096.0f), &s, &c);
        twq[TWPHYS(i)] = make_float2(c, s);
    }
    __syncthreads();

#pragma unroll 1
    for (int rr = 0; rr < ROWS_PER_WG; ++rr){
        const int row = blockIdx.x * ROWS_PER_WG + rr;
        const float2* xr2 = (const float2*)(x + (size_t)row * NFEAT);

        // ---- forward stage 1 (Ns=1) fused with global load: z[m]=x[2m]+i x[2m+1]
        {
            float2 v[8];
#pragma unroll
            for (int r = 0; r < 8; ++r) v[r] = xr2[t + 256*r];
            fft8<-1>(v);
            const int idxD = t << 3;
#pragma unroll
            for (int r = 0; r < 8; ++r) bufB[SWZ(idxD + r)] = v[r];
        }
        __syncthreads();

        stage8<-1,8 >(bufB, bufA, twq, t); __syncthreads();
        stage8<-1,64>(bufA, bufB, twq, t); __syncthreads();

        // ---- forward stage 4: radix-4, Ns=512 (bufB -> bufA), j = t and t+256
#pragma unroll
        for (int h = 0; h < 2; ++h){
            const int j = t + 256*h;
            float2 v0 = bufB[SWZ(j)];
            float2 v1 = cmul(bufB[SWZ(j +  512)], tw2048<-1>(twq, j));
            float2 v2 = cmul(bufB[SWZ(j + 1024)], tw2048<-1>(twq, 2*j));
            float2 v3 = cmul(bufB[SWZ(j + 1536)], tw2048<-1>(twq, 3*j));
            fft4<-1>(v0,v1,v2,v3);
            bufA[SWZ(j)]        = v0;
            bufA[SWZ(j +  512)] = v1;
            bufA[SWZ(j + 1024)] = v2;
            bufA[SWZ(j + 1536)] = v3;
        }
        __syncthreads();

        // ---- spectral: untangle rfft bins (k<1024; rest masked), apply H,
        //      retangle into packed inverse spectrum.  bufA -> bufB.
#pragma unroll
        for (int q = 0; q < 4; ++q){
            int k = t + THREADS*q;
            if (k == 0){
                float2 z0 = bufA[SWZ(0)];
                float X0 = z0.x + z0.y;
                float Y0 = X0 * Hr[0];
                bufB[SWZ(0)]    = make_float2(0.5f*Y0, 0.5f*Y0);
                bufB[SWZ(1024)] = make_float2(0.f, 0.f);
            } else {
                float2 zk = bufA[SWZ(k)];
                float2 zm = bufA[SWZ(2048 - k)];
                float2 w  = twq[TWPHYS(k)];                  // e^{-2pi i k/4096}
                float2 A = make_float2(0.5f*(zk.x + zm.x), 0.5f*(zk.y - zm.y));
                float2 B = make_float2(0.5f*(zk.x - zm.x), 0.5f*(zk.y + zm.y));
                float2 wB = cmul(w, B);
                float2 X = make_float2(A.x + wB.y, A.y - wB.x);
                float2 H = make_float2(Hr[k], Hi[k]);
                float2 Y = cmul(X, H);
                float2 f1 = make_float2(1.f + w.y,  w.x);
                float2 f2 = make_float2(1.f - w.y,  w.x);
                float2 Yc = make_float2(Y.x, -Y.y);
                float2 zy1 = cmul(Y,  f1);
                float2 zy2 = cmul(Yc, f2);
                bufB[SWZ(k)]        = make_float2(0.5f*zy1.x, 0.5f*zy1.y);
                bufB[SWZ(2048 - k)] = make_float2(0.5f*zy2.x, 0.5f*zy2.y);
            }
        }
        __syncthreads();

        stage8<1,1 >(bufB, bufA, twq, t); __syncthreads();
        stage8<1,8 >(bufA, bufB, twq, t); __syncthreads();
        stage8<1,64>(bufB, bufA, twq, t); __syncthreads();

        // ---- inverse stage 4 (radix-4, Ns=512) fused with store + scale + bias
        float2* yr2 = (float2*)(out + (size_t)row * NFEAT);
        const float2* br2 = (const float2*)bias;
        const float inv = (1.0f/2048.0f);
#pragma unroll
        for (int h = 0; h < 2; ++h){
            const int j = t + 256*h;
            float2 v0 = bufA[SWZ(j)];
            float2 v1 = cmul(bufA[SWZ(j +  512)], tw2048<1>(twq, j));
            float2 v2 = cmul(bufA[SWZ(j + 1024)], tw2048<1>(twq, 2*j));
            float2 v3 = cmul(bufA[SWZ(j + 1536)], tw2048<1>(twq, 3*j));
            fft4<1>(v0,v1,v2,v3);
            float2 vv[4] = {v0,v1,v2,v3};
#pragma unroll
            for (int r = 0; r < 4; ++r){
                int mo = j + 512*r;                 // output packed index
                float2 b = br2[mo];
                float2 o;
                o.x = fmaf(vv[r].x, inv, b.x);
                o.y = fmaf(vv[r].y, inv, b.y);
                yr2[mo] = o;
            }
        }
        // No end-of-row barrier needed: next row's first LDS write hits bufB,
        // which was last read before the barrier preceding inverse stage 3;
        // bufA reads above are protected by the barrier after next row's
        // forward stage 1 (which writes only bufB).
    }
}

extern "C" void kernel_launch(void* const* d_in, const int* in_sizes, int n_in,
                              void* d_out, int out_size, void* d_ws, size_t ws_size,
                              hipStream_t stream) {
    const float* x    = (const float*)d_in[0];
    const float* Hr   = (const float*)d_in[1];
    const float* Hi   = (const float*)d_in[2];
    const float* bias = (const float*)d_in[3];
    float* out        = (float*)d_out;

    const int n_rows = in_sizes[0] / NFEAT;   // 8192 at reference shape
    dim3 grid(n_rows / ROWS_PER_WG), block(THREADS);
    hipLaunchKernelGGL(rfft_circ_kernel, grid, block, 0, stream,
                       x, Hr, Hi, bias, out);
}